// Round 9
// baseline (1022.877 us; speedup 1.0000x reference)
//
#include <hip/hip_runtime.h>
#include <stdint.h>

typedef float f32x4 __attribute__((ext_vector_type(4)));
typedef long long2_t __attribute__((ext_vector_type(2)));
typedef unsigned int uint;
typedef unsigned long long ull;

#define NB 2048
#define NS 128
#define NI 8
#define NH 256
#define NG 1024   // 4*H
#define NK 50

#define A_SC 16.0f
#define W_SC 32.0f
#define INV_SC (1.0f/(A_SC*W_SC))

// IDM constants
#define DT_    0.1f
#define V_DES_ 12.64798288f
#define T_HW_  0.50284384f
#define A_MAX_ 0.10033688f
#define B_SAFE_ 4.98937183f
#define S0_    0.13082412f

// LDS h-stage [32 rows][256 B]; 16B-granule XOR swizzle (r8-proven)
#define HADDR16(row, boff) (((row) << 8) + (((((boff) >> 4) ^ ((row) & 15)) & 15) << 4) + ((boff) & 15))

__device__ __forceinline__ uint8_t f2fp8(float v) {
    int r = __builtin_amdgcn_cvt_pk_fp8_f32(v, v, 0, false);
    return (uint8_t)(r & 0xff);
}
__device__ __forceinline__ float sigm(float x) { return 1.0f / (1.0f + __expf(-x)); }
__device__ __forceinline__ float tanh_f(float x) {
    x = fminf(fmaxf(x, -15.0f), 15.0f);
    float e = __expf(2.0f * x);
    return (e - 1.0f) / (e + 1.0f);
}

// ---------------- pre-pass kernels ----------------
__global__ void k_pack(const float* __restrict__ W, uint8_t* __restrict__ out,
                       int tiles, int KB, int Nsrc, int Ksrc) {
    int gid = blockIdx.x * 256 + threadIdx.x;
    int total = tiles * KB * 64;
    if (gid >= total) return;
    int lane = gid & 63;
    int kb   = (gid >> 6) % KB;
    int tile = gid / (64 * KB);
    int n = tile * 16 + (lane & 15);
    int kbase = kb * 32 + (lane >> 4) * 8;
    uint64_t wbits = 0;
    #pragma unroll
    for (int j = 0; j < 8; ++j) {
        int k = kbase + j;
        float v = (n < Nsrc && k < Ksrc) ? W[(size_t)n * Ksrc + k] * W_SC : 0.0f;
        wbits |= ((uint64_t)f2fp8(v)) << (8 * j);
    }
    *(uint64_t*)(out + (size_t)gid * 8) = wbits;
}

__global__ void k_bias(const float* __restrict__ bih0, const float* __restrict__ bhh0,
                       const float* __restrict__ bih1, const float* __restrict__ bhh1,
                       float* __restrict__ b0, float* __restrict__ b1) {
    int i = blockIdx.x * 256 + threadIdx.x;
    if (i < NG) b0[i] = bih0[i] + bhh0[i];
    else if (i < 2 * NG) b1[i - NG] = bih1[i - NG] + bhh1[i - NG];
}

__global__ void k_x8(const float* __restrict__ x, uint8_t* __restrict__ x8) {
    int i = blockIdx.x * 256 + threadIdx.x;
    if (i < NB * NS * NI) x8[i] = f2fp8(x[i] * A_SC);
}

// ------------- in-register-nonlin weight-stationary LSTM -------------
// 256 WGs = 64 batch-groups (32 rows) x 4 gate-slices (64 units), same-XCD
// cluster {g, g+64, g+128, g+192}. Wave = (unit-tile ut, row-half rh): owns
// 16 units x ALL 4 gates x 16 rows -> MFMA C-layout gives each lane all 4
// gates of its (row,unit) -> cell update fully in registers. NO gate-staging
// LDS, NO staging barriers. Weights: 96 frags = 192 AGPR pinned; Wih0 re-read
// from L2 per phase. 3 __syncthreads + 1 counter wait per phase.
__global__ __launch_bounds__(512, 2)
void k_lstm9(const uint8_t* __restrict__ x8,
             const uint8_t* __restrict__ Wih0P, const uint8_t* __restrict__ Whh0P,
             const uint8_t* __restrict__ Wih1P, const uint8_t* __restrict__ Whh1P,
             const uint8_t* __restrict__ WfcP,
             const float* __restrict__ bias0, const float* __restrict__ bias1,
             const float* __restrict__ bfc,
             uint8_t* __restrict__ h0g, uint8_t* __restrict__ h1g,
             uint* __restrict__ ctrs, float* __restrict__ out) {
    __shared__ uint8_t h0st[8192];   // h0[p-1], fp8, HADDR16 layout
    __shared__ uint8_t h1st[8192];   // h1[p-2]

    const int tid  = threadIdx.x;
    const int lane = tid & 63, w = tid >> 6;
    const int lrow = lane & 15, kgrp = lane >> 4;
    const int grp  = blockIdx.x & 63, slc = blockIdx.x >> 6;   // same-XCD cluster
    const int rowbase = grp * 32;
    const int ut = w & 3, rh = w >> 2;        // wave: unit-tile, row-half
    const int gu = slc * 64 + ut * 16 + lrow; // this lane's global unit

    // ---- persistent weight fragments: 96 frags = 192 AGPR, pinned ----
    long wH0[4][8], wI1[4][8], wH1[4][8];
    #pragma unroll
    for (int g = 0; g < 4; ++g) {
        const int T = g * 16 + slc * 4 + ut;
        #pragma unroll
        for (int kb = 0; kb < 8; ++kb) {
            wH0[g][kb] = *(const long*)(Whh0P + (((size_t)T * 8 + kb) * 64 + lane) * 8);
            wI1[g][kb] = *(const long*)(Wih1P + (((size_t)T * 8 + kb) * 64 + lane) * 8);
            wH1[g][kb] = *(const long*)(Whh1P + (((size_t)T * 8 + kb) * 64 + lane) * 8);
        }
    }
    #pragma unroll
    for (int g = 0; g < 4; ++g)
        #pragma unroll
        for (int kb = 0; kb < 8; ++kb)
            asm volatile("" : "+a"(wH0[g][kb]), "+a"(wI1[g][kb]), "+a"(wH1[g][kb]));

    float bs0[4], bs1[4];
    #pragma unroll
    for (int g = 0; g < 4; ++g) { bs0[g] = bias0[g * 256 + gu]; bs1[g] = bias1[g * 256 + gu]; }
    float c0v[4] = {0,0,0,0}, c1v[4] = {0,0,0,0};

    { int4 z = {0,0,0,0}; ((int4*)h0st)[tid] = z; ((int4*)h1st)[tid] = z; }
    __syncthreads();

    uint8_t* const h0gg = h0g + (size_t)grp * 16384;   // [parity][32][256]
    uint8_t* const h1gg = h1g + (size_t)grp * 16384;
    uint* const ctr = ctrs + grp * 32;
    uint tgt = 0;

    const int rrow = tid & 31, seg = tid >> 5;         // restage: 16B/thread/stream
    const int rkb = seg >> 1, rkg = (seg & 1) << 1;
    const int rboff0 = rkg * 64 + rkb * 8, rboff1 = (rkg + 1) * 64 + rkb * 8;
    const int abase = (rh * 16 + lrow) << 8;           // A-frag LDS row base
    const size_t xrow = (size_t)(rowbase + rh * 16 + lrow) * (NS * NI);
    // publish addrs: 4 rows of unit gu
    const int prow = rh * 16 + kgrp * 4;

    for (int p = 0; p <= NS; ++p) {
        // ===== layer 0 (t=p): x_t@Wih0^T + h0(p-1)@Whh0^T, acc in-register =====
        if (p < NS) {
            long xf = 0;
            if (kgrp == 0) xf = *(const long*)(x8 + xrow + p * 8);
            long wi0[4];
            #pragma unroll
            for (int g = 0; g < 4; ++g)
                wi0[g] = *(const long*)(Wih0P + ((size_t)(g * 16 + slc * 4 + ut) * 64 + lane) * 8);
            f32x4 acc[4];
            #pragma unroll
            for (int g = 0; g < 4; ++g) acc[g] = (f32x4){0,0,0,0};
            #pragma unroll
            for (int kbh = 0; kbh < 4; ++kbh) {
                const int gsw = ((((kgrp << 2) + kbh) ^ lrow) & 15) << 4;
                long2_t q = *(const long2_t*)&h0st[abase + gsw];
                #pragma unroll
                for (int g = 0; g < 4; ++g) {
                    acc[g] = __builtin_amdgcn_mfma_f32_16x16x32_fp8_fp8(q.x, wH0[g][2*kbh],   acc[g], 0, 0, 0);
                    acc[g] = __builtin_amdgcn_mfma_f32_16x16x32_fp8_fp8(q.y, wH0[g][2*kbh+1], acc[g], 0, 0, 0);
                }
            }
            #pragma unroll
            for (int g = 0; g < 4; ++g)
                acc[g] = __builtin_amdgcn_mfma_f32_16x16x32_fp8_fp8(xf, wi0[g], acc[g], 0, 0, 0);
            // in-register nonlin0 -> publish h0(p)
            uint8_t* dst = h0gg + (size_t)(p & 1) * 8192;
            #pragma unroll
            for (int r = 0; r < 4; ++r) {
                float iv = fmaf(acc[0][r], INV_SC, bs0[0]);
                float fv = fmaf(acc[1][r], INV_SC, bs0[1]);
                float gv = fmaf(acc[2][r], INV_SC, bs0[2]);
                float ov = fmaf(acc[3][r], INV_SC, bs0[3]);
                float c = sigm(fv) * c0v[r] + sigm(iv) * tanh_f(gv);
                c0v[r] = c;
                float hh = sigm(ov) * tanh_f(c);
                __hip_atomic_store(dst + (prow + r) * 256 + gu, f2fp8(hh * A_SC),
                                   __ATOMIC_RELAXED, __HIP_MEMORY_SCOPE_AGENT);
            }
        }

        // ===== layer 1 (t=p-1): h0(p-1)@Wih1^T + h1(p-2)@Whh1^T =====
        if (p >= 1) {
            f32x4 acc[4];
            #pragma unroll
            for (int g = 0; g < 4; ++g) acc[g] = (f32x4){0,0,0,0};
            #pragma unroll
            for (int kbh = 0; kbh < 4; ++kbh) {
                const int gsw = ((((kgrp << 2) + kbh) ^ lrow) & 15) << 4;
                long2_t q = *(const long2_t*)&h0st[abase + gsw];
                long2_t s = *(const long2_t*)&h1st[abase + gsw];
                #pragma unroll
                for (int g = 0; g < 4; ++g) {
                    acc[g] = __builtin_amdgcn_mfma_f32_16x16x32_fp8_fp8(q.x, wI1[g][2*kbh],   acc[g], 0, 0, 0);
                    acc[g] = __builtin_amdgcn_mfma_f32_16x16x32_fp8_fp8(q.y, wI1[g][2*kbh+1], acc[g], 0, 0, 0);
                    acc[g] = __builtin_amdgcn_mfma_f32_16x16x32_fp8_fp8(s.x, wH1[g][2*kbh],   acc[g], 0, 0, 0);
                    acc[g] = __builtin_amdgcn_mfma_f32_16x16x32_fp8_fp8(s.y, wH1[g][2*kbh+1], acc[g], 0, 0, 0);
                }
            }
            // in-register nonlin1 -> publish h1(p-1)
            uint8_t* dst = h1gg + (size_t)((p + 1) & 1) * 8192;
            #pragma unroll
            for (int r = 0; r < 4; ++r) {
                float iv = fmaf(acc[0][r], INV_SC, bs1[0]);
                float fv = fmaf(acc[1][r], INV_SC, bs1[1]);
                float gv = fmaf(acc[2][r], INV_SC, bs1[2]);
                float ov = fmaf(acc[3][r], INV_SC, bs1[3]);
                float c = sigm(fv) * c1v[r] + sigm(iv) * tanh_f(gv);
                c1v[r] = c;
                float hh = sigm(ov) * tanh_f(c);
                __hip_atomic_store(dst + (prow + r) * 256 + gu, f2fp8(hh * A_SC),
                                   __ATOMIC_RELAXED, __HIP_MEMORY_SCOPE_AGENT);
            }
        }
        __syncthreads();   // S1: publishes drained (vmcnt(0)), LDS reads done

        // ===== cluster barrier (single counter) =====
        tgt += 4;
        if (tid == 0) {
            __hip_atomic_fetch_add(ctr, 1u, __ATOMIC_RELAXED, __HIP_MEMORY_SCOPE_AGENT);
            uint gd = 0;
            while (__hip_atomic_load(ctr, __ATOMIC_RELAXED, __HIP_MEMORY_SCOPE_AGENT) < tgt) {
                __builtin_amdgcn_s_sleep(1);
                if (++gd > (1u << 24)) break;
            }
        }
        __syncthreads();   // S2: barrier passed

        // ===== combined restage: h0(p) par(p&1), h1(p-1) par((p+1)&1) =====
        {
            const uint8_t* s0 = h0gg + (size_t)(p & 1) * 8192 + rrow * 256 + seg * 16;
            const uint8_t* s1 = h1gg + (size_t)((p + 1) & 1) * 8192 + rrow * 256 + seg * 16;
            ull a0 = __hip_atomic_load((const ull*)s0,       __ATOMIC_RELAXED, __HIP_MEMORY_SCOPE_AGENT);
            ull a1 = __hip_atomic_load((const ull*)(s0 + 8), __ATOMIC_RELAXED, __HIP_MEMORY_SCOPE_AGENT);
            ull b0 = __hip_atomic_load((const ull*)s1,       __ATOMIC_RELAXED, __HIP_MEMORY_SCOPE_AGENT);
            ull b1 = __hip_atomic_load((const ull*)(s1 + 8), __ATOMIC_RELAXED, __HIP_MEMORY_SCOPE_AGENT);
            *(ull*)&h0st[HADDR16(rrow, rboff0)] = a0;
            *(ull*)&h0st[HADDR16(rrow, rboff1)] = a1;
            *(ull*)&h1st[HADDR16(rrow, rboff0)] = b0;
            *(ull*)&h1st[HADDR16(rrow, rboff1)] = b1;
        }
        __syncthreads();   // S3: stages ready for next phase
    }

    // ===== FC head: y = h1(127) @ Wfc^T + bfc (h1st holds h1(127)) =====
    if (w < 2) {
        f32x4 a = {0,0,0,0};
        #pragma unroll
        for (int kbh = 0; kbh < 4; ++kbh) {
            const int gsw = ((((kgrp << 2) + kbh) ^ lrow) & 15) << 4;
            long2_t q = *(const long2_t*)&h1st[((w * 16 + lrow) << 8) + gsw];
            long b0_ = *(const long*)(WfcP + (((size_t)slc * 8 + 2 * kbh) * 64 + lane) * 8);
            long b1_ = *(const long*)(WfcP + (((size_t)slc * 8 + 2 * kbh + 1) * 64 + lane) * 8);
            a = __builtin_amdgcn_mfma_f32_16x16x32_fp8_fp8(q.x, b0_, a, 0, 0, 0);
            a = __builtin_amdgcn_mfma_f32_16x16x32_fp8_fp8(q.y, b1_, a, 0, 0, 0);
        }
        const int col = slc * 16 + lrow;
        if (col < NK) {
            float bb = bfc[col];
            #pragma unroll
            for (int r = 0; r < 4; ++r)
                out[(size_t)(rowbase + w * 16 + kgrp * 4 + r) * NK + col] = a[r] * INV_SC + bb;
        }
    }
}

// ---------------- IDM rollout (exact fp32) ----------------
__global__ void k_idm(const float* __restrict__ x, const float* __restrict__ s0,
                      const float* __restrict__ vl, float* __restrict__ out) {
    int b = blockIdx.x * 256 + threadIdx.x;
    if (b >= NB) return;
    float v = x[(size_t)b * NS * NI + (NS - 1) * NI + 0];
    float s = s0[b];
    float vlead = vl[b];
    const float den = 2.0f * sqrtf(A_MAX_ * B_SAFE_) + 1e-6f;
    float* o = out + (size_t)NB * NK + (size_t)b * NK;
    #pragma unroll 1
    for (int k = 0; k < NK; ++k) {
        float dv = vlead - v;
        float sc = fmaxf(s, 1e-6f);
        float ss = fmaxf(S0_ + v * T_HW_ + v * dv / den, 0.0f);
        float a = A_MAX_ * (1.0f - v / V_DES_ - (ss / sc) * (ss / sc));
        v = fmaxf(v + DT_ * a, 0.0f);
        s = fmaxf(s + dv * DT_, 1e-6f);
        o[k] = v;
    }
}

// ---------------- launch ----------------
extern "C" void kernel_launch(void* const* d_in, const int* in_sizes, int n_in,
                              void* d_out, int out_size, void* d_ws, size_t ws_size,
                              hipStream_t stream) {
    const float* x    = (const float*)d_in[0];
    const float* s0   = (const float*)d_in[1];
    const float* vl   = (const float*)d_in[2];
    const float* Wih0 = (const float*)d_in[3];
    const float* Whh0 = (const float*)d_in[4];
    const float* bih0 = (const float*)d_in[5];
    const float* bhh0 = (const float*)d_in[6];
    const float* Wih1 = (const float*)d_in[7];
    const float* Whh1 = (const float*)d_in[8];
    const float* bih1 = (const float*)d_in[9];
    const float* bhh1 = (const float*)d_in[10];
    const float* Wfc  = (const float*)d_in[11];
    const float* bfc  = (const float*)d_in[12];
    float* out = (float*)d_out;

    uint8_t* ws = (uint8_t*)d_ws;
    size_t off = 0;
    auto alloc = [&](size_t n) { uint8_t* p = ws + off; off += (n + 255) & ~(size_t)255; return p; };
    uint8_t* Wih0P = alloc(64 * 1 * 64 * 8);
    uint8_t* Whh0P = alloc(64 * 8 * 64 * 8);
    uint8_t* Wih1P = alloc(64 * 8 * 64 * 8);
    uint8_t* Whh1P = alloc(64 * 8 * 64 * 8);
    uint8_t* WfcP  = alloc(4 * 8 * 64 * 8);
    float* b0 = (float*)alloc(NG * 4);
    float* b1 = (float*)alloc(NG * 4);
    uint8_t* x8 = alloc((size_t)NB * NS * NI);
    // h exchange zone (memset each launch): h0g | h1g | ctrs, contiguous
    uint8_t* h0g = alloc((size_t)64 * 16384);
    uint8_t* h1g = alloc((size_t)64 * 16384);
    uint*    ctrs = (uint*)alloc(64 * 32 * 4);
    size_t hz = (size_t)(((uint8_t*)ctrs + 64 * 32 * 4) - h0g);

    k_pack<<<(64 * 1 * 64 + 255) / 256, 256, 0, stream>>>(Wih0, Wih0P, 64, 1, NG, NI);
    k_pack<<<(64 * 8 * 64 + 255) / 256, 256, 0, stream>>>(Whh0, Whh0P, 64, 8, NG, NH);
    k_pack<<<(64 * 8 * 64 + 255) / 256, 256, 0, stream>>>(Wih1, Wih1P, 64, 8, NG, NH);
    k_pack<<<(64 * 8 * 64 + 255) / 256, 256, 0, stream>>>(Whh1, Whh1P, 64, 8, NG, NH);
    k_pack<<<(4 * 8 * 64 + 255) / 256, 256, 0, stream>>>(Wfc, WfcP, 4, 8, NK, NH);
    k_bias<<<(2 * NG + 255) / 256, 256, 0, stream>>>(bih0, bhh0, bih1, bhh1, b0, b1);
    k_x8<<<(NB * NS * NI + 255) / 256, 256, 0, stream>>>(x, x8);
    hipMemsetAsync(h0g, 0, hz, stream);

    void* kargs[] = { (void*)&x8, (void*)&Wih0P, (void*)&Whh0P, (void*)&Wih1P, (void*)&Whh1P,
                      (void*)&WfcP, (void*)&b0, (void*)&b1, (void*)&bfc,
                      (void*)&h0g, (void*)&h1g, (void*)&ctrs, (void*)&out };
    hipError_t ce = hipLaunchCooperativeKernel((const void*)k_lstm9, dim3(256), dim3(512), kargs, 0, stream);
    if (ce != hipSuccess) {
        k_lstm9<<<256, 512, 0, stream>>>(x8, Wih0P, Whh0P, Wih1P, Whh1P, WfcP, b0, b1, bfc, h0g, h1g, ctrs, out);
    }
    k_idm<<<(NB + 255) / 256, 256, 0, stream>>>(x, s0, vl, out);
}